// Round 6
// baseline (126.303 us; speedup 1.0000x reference)
//
#include <hip/hip_runtime.h>
#include <math.h>

__device__ __forceinline__ double rdin(const void* p, int idx, bool isdbl) {
  return isdbl ? ((const double*)p)[idx] : (double)((const float*)p)[idx];
}

__device__ __forceinline__ bool detect_dbl(const void* xv) {
  // f64 data reinterpreted as f32 words shows wild exponents in the low
  // (mantissa) words; true f32 N(0,1) never exceeds 1e6. 64 words => P(miss)~2e-8.
  const float* xq = (const float*)xv;
  bool isdbl = false;
  for (int j = 0; j < 64; ++j) {
    float a = fabsf(xq[j]);
    if (!(a < 1e6f)) isdbl = true;
  }
  return isdbl;
}

// ---------------------------------------------------------------------------
// Fully fused: grid = B*16 blocks x 64 threads (16 waves/CU). Block bx
// handles sample i = bx>>4, slice blk = bx&15 (j = blk>>2, kbase=(blk&3)*16).
// Every block redundantly runs the fp32 eigensolve + Jacobian for its sample
// (latency-bound; 16 co-resident waves hide each other's stalls), then stores
// its 4 KB slice of I_k directly. blk==0 also stores I_b = M.
// LDS ~9.6 KB/block -> 16 blocks/CU.
// ---------------------------------------------------------------------------
__global__ __launch_bounds__(64, 4) void fi_fused(
    const void* __restrict__ xv,
    const void* __restrict__ kv,
    const void* __restrict__ bv,
    float* __restrict__ out, int Bn)
{
  const int bx  = blockIdx.x;
  const int i   = bx >> 4;
  const int blk = bx & 15;
  const int t   = threadIdx.x;         // 0..63

  __shared__ float pw[64];
  __shared__ float Hre[8][8], Him[8][8];
  __shared__ float Vre[8][8], Vim[8][8];
  __shared__ float ampre[8], ampim[8], invPs[8], ev[8];
  __shared__ __align__(16) float gk[64][8], hk[64][8];  // Jacobian cols, k-major
  __shared__ __align__(16) float scratch[1024];         // F,G then reused as Ms
  float (*Fre)[8] = (float(*)[8])(scratch);             // [8][8]
  float (*Fim)[8] = (float(*)[8])(scratch + 64);
  float (*Gre)[8] = (float(*)[8])(scratch + 128);
  float (*Gim)[8] = (float(*)[8])(scratch + 192);
  float (*Ms)[64] = (float(*)[64])(scratch);            // [16][64], after F/G die

  const bool isdbl = detect_dbl(xv);

  // ---- pw = x @ K + bias ---------------------------------------------------
  {
    float acc = (float)rdin(bv, t, isdbl);
    #pragma unroll
    for (int j = 0; j < 4; ++j)
      acc += (float)rdin(xv, i*4 + j, isdbl) * (float)rdin(kv, j*64 + t, isdbl);
    pw[t] = acc;
  }
  __syncthreads();

  // ---- build H = sum_k pw_k P_k (analytic Pauli strings), init V = I ------
  {
    int r = t >> 3, c = t & 7;
    int m = r ^ c;
    float hre = 0.0f, him = 0.0f;
    for (int u = 0; u < 8; ++u) {
      int k = 0;
      float pr = 1.0f, pim = 0.0f;
      #pragma unroll
      for (int q = 0; q < 3; ++q) {
        int bit = 2 - q;
        int f  = (m >> bit) & 1;
        int ch = (u >> bit) & 1;
        int rb = (r >> bit) & 1;
        int d  = f ? (ch ? 2 : 1) : (ch ? 3 : 0);  // I=0,X=1,Y=2,Z=3
        k = (k << 2) | d;
        if (d == 2) {
          float nr = rb ? -pim : pim;
          float ni = rb ?  pr  : -pr;
          pr = nr; pim = ni;
        } else if (d == 3 && rb) { pr = -pr; pim = -pim; }
      }
      float w = pw[k];
      hre += w * pr; him += w * pim;
    }
    Hre[r][c] = hre; Him[r][c] = him;
    Vre[r][c] = (r == c) ? 1.0f : 0.0f;
    Vim[r][c] = 0.0f;
  }
  __syncthreads();

  // ---- complex Hermitian Jacobi, fp32, closed-form round-robin pairs ------
  const int tl = t & 31;
  const int pp = tl >> 3, j = tl & 7;
  #pragma unroll
  for (int sweep = 0; sweep < 4; ++sweep) {
    #pragma unroll
    for (int round = 0; round < 7; ++round) {
      int p, q;
      if (pp == 0) { p = 7; q = round; }
      else {
        p = round + pp;     if (p >= 7) p -= 7;
        q = round + 7 - pp; if (q >= 7) q -= 7;
      }
      float cc = 1.0f, sg = 0.0f, wr = 1.0f, wi = 0.0f;
      {
        float a = Hre[p][p], b = Hre[q][q];
        float zr = Hre[p][q], zi = Him[p][q];
        float r2 = zr*zr + zi*zi;
        if (r2 > 1e-24f) {
          float rr = sqrtf(r2);
          wr = zr / rr; wi = zi / rr;
          float th = (b - a) / (2.0f * rr);
          float tt = ((th >= 0.0f) ? 1.0f : -1.0f) / (fabsf(th) + sqrtf(1.0f + th*th));
          cc = 1.0f / sqrtf(1.0f + tt*tt);
          sg = tt * cc;
        }
      }
      float e0r, e0i, e1r, e1i;
      if (t < 32) { e0r = Hre[j][p]; e0i = Him[j][p]; e1r = Hre[j][q]; e1i = Him[j][q]; }
      else        { e0r = Vre[j][p]; e0i = Vim[j][p]; e1r = Vre[j][q]; e1i = Vim[j][q]; }
      __syncthreads();
      if (t < 32) {                      // H column update: A <- A*U
        Hre[j][p] = cc*e0r - sg*(wr*e1r + wi*e1i);
        Him[j][p] = cc*e0i - sg*(wr*e1i - wi*e1r);
        Hre[j][q] = sg*(wr*e0r - wi*e0i) + cc*e1r;
        Him[j][q] = sg*(wr*e0i + wi*e0r) + cc*e1i;
      } else {                           // V column update: V <- V*U
        Vre[j][p] = cc*e0r - sg*(wr*e1r + wi*e1i);
        Vim[j][p] = cc*e0i - sg*(wr*e1i - wi*e1r);
        Vre[j][q] = sg*(wr*e0r - wi*e0i) + cc*e1r;
        Vim[j][q] = sg*(wr*e0i + wi*e0r) + cc*e1i;
      }
      __syncthreads();
      if (t < 32) {                      // H row update: A <- U^H * A
        float rpr = Hre[p][j], rpi = Him[p][j];
        float rqr = Hre[q][j], rqi = Him[q][j];
        Hre[p][j] = cc*rpr - sg*(wr*rqr - wi*rqi);
        Him[p][j] = cc*rpi - sg*(wr*rqi + wi*rqr);
        Hre[q][j] = sg*(wr*rpr + wi*rpi) + cc*rqr;
        Him[q][j] = sg*(wr*rpi - wi*rpr) + cc*rqi;
      }
      __syncthreads();
    }
  }

  if (t < 8) ev[t] = Hre[t][t];
  __syncthreads();

  // ---- F (Daleckii-Krein) + amp + 1/P -------------------------------------
  {
    int s = t >> 3, u = t & 7;
    float dm = 0.5f * (ev[s] - ev[u]);
    float av = 0.5f * (ev[s] + ev[u]);
    float sc = (fabsf(dm) < 1e-3f) ? (1.0f - dm*dm*(1.0f/6.0f)) : (__sinf(dm)/dm);
    Fre[s][u] =  __cosf(av) * sc;
    Fim[s][u] = -__sinf(av) * sc;
  }
  if (t < 8) {
    float are = 0.0f, aim = 0.0f;
    #pragma unroll
    for (int s = 0; s < 8; ++s) {
      float ce = __cosf(ev[s]), se = -__sinf(ev[s]);
      float c0r = Vre[0][s], c0i = -Vim[0][s];
      float wr2 = c0r*ce - c0i*se;
      float wi2 = c0r*se + c0i*ce;
      float vjr = Vre[t][s], vji = Vim[t][s];
      are += vjr*wr2 - vji*wi2;
      aim += vjr*wi2 + vji*wr2;
    }
    ampre[t] = are; ampim[t] = aim;
    float P = are*are + aim*aim;
    invPs[t] = 1.0f / fmaxf(P, 1e-30f);
  }
  __syncthreads();

  // ---- G[s][rho] = sum_u V[rho][u] F[s][u] conj(V[0][u]) ------------------
  {
    int s = t >> 3, rho = t & 7;
    float gr = 0.0f, gi = 0.0f;
    #pragma unroll
    for (int u = 0; u < 8; ++u) {
      float c0r = Vre[0][u], c0i = -Vim[0][u];
      float fr = Fre[s][u], fi = Fim[s][u];
      float fcr = fr*c0r - fi*c0i;
      float fci = fr*c0i + fi*c0r;
      float vr = Vre[rho][u], vi = Vim[rho][u];
      gr += vr*fcr - vi*fci;
      gi += vr*fci + vi*fcr;
    }
    Gre[s][rho] = gr; Gim[s][rho] = gi;
  }
  __syncthreads();

  // ---- Jacobian column k = t: gcol[p] in registers, g,h to LDS ------------
  float gcol[8];
  {
    const int k = t;
    const int d0 = (k >> 4) & 3, d1 = (k >> 2) & 3, d2 = k & 3;
    const int m = ((((d0 == 1) | (d0 == 2)) ? 1 : 0) << 2)
                | ((((d1 == 1) | (d1 == 2)) ? 1 : 0) << 1)
                |  (((d2 == 1) | (d2 == 2)) ? 1 : 0);
    float yre[8], yim[8];
    #pragma unroll
    for (int s = 0; s < 8; ++s) { yre[s] = 0.0f; yim[s] = 0.0f; }
    #pragma unroll
    for (int r = 0; r < 8; ++r) {
      float pr = 1.0f, pim = 0.0f;       // ph_k(r), in {±1, ±i}
      const int dd0[3] = {d0, d1, d2};
      #pragma unroll
      for (int q = 0; q < 3; ++q) {
        int rb = (r >> (2 - q)) & 1;
        int d = dd0[q];
        if (d == 2) {
          float nr = rb ? -pim : pim;
          float ni = rb ?  pr  : -pr;
          pr = nr; pim = ni;
        } else if (d == 3 && rb) { pr = -pr; pim = -pim; }
      }
      int rm = r ^ m;
      #pragma unroll
      for (int s = 0; s < 8; ++s) {      // y_s += conj(V[r][s]) ph G[s][r^m]
        float vr = Vre[r][s], vi = -Vim[r][s];
        float gr2 = Gre[s][rm], gi2 = Gim[s][rm];
        float ar = pr*gr2 - pim*gi2;
        float ai = pr*gi2 + pim*gr2;
        yre[s] += vr*ar - vi*ai;
        yim[s] += vr*ai + vi*ar;
      }
    }
    #pragma unroll
    for (int p = 0; p < 8; ++p) {        // damp_p = sum_s V[p][s] * (-i*y_s)
      float dr = 0.0f, di = 0.0f;
      #pragma unroll
      for (int s = 0; s < 8; ++s) {
        float ysr =  yim[s], ysi = -yre[s];   // * (-i)
        float vr = Vre[p][s], vi = Vim[p][s];
        dr += vr*ysr - vi*ysi;
        di += vr*ysi + vi*ysr;
      }
      float gg = 2.0f * (ampre[p]*dr + ampim[p]*di);
      gcol[p] = gg;
      gk[k][p] = gg;
      hk[k][p] = gg * invPs[p];
    }
  }
  __syncthreads();                        // G dead from here; scratch reusable

  // ---- blk==0: I_b row t = M[t][:] = gcol . h[:][:], dwordx4 stores -------
  if (blk == 0) {
    float* ob = out + (size_t)Bn * 65536 + (size_t)i * 4096 + (size_t)t * 64;
    #pragma unroll
    for (int m4 = 0; m4 < 16; ++m4) {
      float4 vv;
      #pragma unroll
      for (int l = 0; l < 4; ++l) {
        int m = m4*4 + l;
        const float4 ha = *(const float4*)&hk[m][0];   // broadcast reads
        const float4 hb = *(const float4*)&hk[m][4];
        (&vv.x)[l] = gcol[0]*ha.x + gcol[1]*ha.y + gcol[2]*ha.z + gcol[3]*ha.w
                   + gcol[4]*hb.x + gcol[5]*hb.y + gcol[6]*hb.z + gcol[7]*hb.w;
      }
      *(float4*)(ob + m4*4) = vv;
    }
  }

  // ---- M slice for this block: Ms[kk][t] = g[:,kbase+kk] . h[:,t] ---------
  {
    const int kbase = (blk & 3) << 4;
    const float4 ha = *(const float4*)&hk[t][0];       // own column of h
    const float4 hb = *(const float4*)&hk[t][4];
    #pragma unroll
    for (int kk = 0; kk < 16; ++kk) {
      const float4 ga = *(const float4*)&gk[kbase + kk][0];  // broadcast
      const float4 gb = *(const float4*)&gk[kbase + kk][4];
      Ms[kk][t] = ga.x*ha.x + ga.y*ha.y + ga.z*ha.z + ga.w*ha.w
                + gb.x*hb.x + gb.y*hb.y + gb.z*hb.z + gb.w*hb.w;
    }
  }
  __syncthreads();

  // ---- stream I_k slice: 64 rows (local), 64 threads => 16 float4/thread --
  // local = it*4 + rg with rg = t>>4 in [0,4): each iteration writes 4 full
  // rows (64 lanes x 16 B = 1 KiB, coalesced). kk = local>>2, l = local&3.
  {
    float xjf = (float)rdin(xv, i*4 + (blk >> 2), isdbl);
    float xx[4];
    #pragma unroll
    for (int l = 0; l < 4; ++l)
      xx[l] = xjf * (float)rdin(xv, i*4 + l, isdbl);

    float* ok = out + (size_t)i * 65536 + (size_t)blk * 4096;
    const int rg = t >> 4;               // 0..3
    const int q4 = (t & 15) << 2;        // 0,4,..,60
    #pragma unroll
    for (int it = 0; it < 16; ++it) {
      int local = it*4 + rg;             // 0..63, all rows covered
      int kk = local >> 2;
      int l  = local & 3;
      const float4 mv = *(const float4*)&Ms[kk][q4];
      float s = xx[l];
      *(float4*)(ok + (size_t)local * 64 + q4) =
          make_float4(s*mv.x, s*mv.y, s*mv.z, s*mv.w);
    }
  }
}

extern "C" void kernel_launch(void* const* d_in, const int* in_sizes, int n_in,
                              void* d_out, int out_size, void* d_ws, size_t ws_size,
                              hipStream_t stream) {
  (void)n_in; (void)d_ws; (void)ws_size; (void)out_size;
  int Bn = in_sizes[0] / 4;   // 256
  fi_fused<<<Bn * 16, 64, 0, stream>>>(d_in[0], d_in[1], d_in[2],
                                       (float*)d_out, Bn);
}

// Round 7
// 114.043 us; speedup vs baseline: 1.1075x; 1.1075x over previous
//
#include <hip/hip_runtime.h>
#include <math.h>

__device__ __forceinline__ double rdin(const void* p, int idx, bool isdbl) {
  return isdbl ? ((const double*)p)[idx] : (double)((const float*)p)[idx];
}

__device__ __forceinline__ bool detect_dbl(const void* xv) {
  // f64 data reinterpreted as f32 words shows wild exponents in the low
  // (mantissa) words; true f32 N(0,1) never exceeds 1e6. 64 words => P(miss)~2e-8.
  const float* xq = (const float*)xv;
  bool isdbl = false;
  for (int j = 0; j < 64; ++j) {
    float a = fabsf(xq[j]);
    if (!(a < 1e6f)) isdbl = true;
  }
  return isdbl;
}

// partner + lead flag for index v (0..7) in circle-method round (0..6)
__device__ __forceinline__ void pairup(int v, int round, int& prt, bool& isp) {
  if (v == 7) { prt = round; isp = true; return; }
  int o = v - round; if (o < 0) o += 7;        // (v-round) mod 7
  if (o == 0) { prt = 7; isp = false; return; }
  int pr = round + 7 - o; if (pr >= 7) pr -= 7;
  prt = pr; isp = (o <= 3);
}

// Jacobi rotation params from a=H[p][p], b=H[q][q], z=H[p][q]
__device__ __forceinline__ void mkparam(float a, float b, float zr, float zi,
                                        float& cc, float& sg, float& wr, float& wi) {
  float r2 = zr*zr + zi*zi;
  if (r2 > 1e-24f) {
    float irr = __builtin_amdgcn_rsqf(r2);
    wr = zr * irr; wi = zi * irr;
    float th = (b - a) * 0.5f * irr;
    float tt = copysignf(__builtin_amdgcn_rcpf(fabsf(th) + sqrtf(1.0f + th*th)), th);
    cc = __builtin_amdgcn_rsqf(1.0f + tt*tt);
    sg = tt * cc;
  } else { cc = 1.0f; sg = 0.0f; wr = 1.0f; wi = 0.0f; }
}

// ---------------------------------------------------------------------------
// Phase 1: one wave (64 threads) per sample. Element-owned Jacobi: lane
// t = 8r+c owns H[r][c], V[r][c]. Per round: ONE batched LDS read group
// (own quadrant partners + both pair-param triples), params computed
// redundantly per lane in registers, row+col rotation applied in one shot,
// ping-pong LDS write, ONE __syncthreads. 4 sweeps x 7 rounds.
// Then Daleckii-Krein Jacobian, h=g/P, I_b = M = g^T h.
// ---------------------------------------------------------------------------
__global__ __launch_bounds__(64) void fi_phase1(
    const void* __restrict__ xv,
    const void* __restrict__ kv,
    const void* __restrict__ bv,
    float* __restrict__ out, int Bn)
{
  const int i = blockIdx.x;
  const int t = threadIdx.x;           // 0..63
  const int r = t >> 3, c = t & 7;

  __shared__ float Sb[2][4][64];       // [buf][Hre,Him,Vre,Vim][r*8+c]
  __shared__ float pw[64];
  __shared__ float FreS[64], FimS[64], GreS[64], GimS[64];
  __shared__ float ampre[8], ampim[8], invPs[8], evs[8];
  __shared__ __align__(16) float gk[64][8], hk[64][8];  // Jacobian cols

  const bool isdbl = detect_dbl(xv);

  // ---- pw = x @ K + bias ---------------------------------------------------
  {
    float acc = (float)rdin(bv, t, isdbl);
    #pragma unroll
    for (int j = 0; j < 4; ++j)
      acc += (float)rdin(xv, i*4 + j, isdbl) * (float)rdin(kv, j*64 + t, isdbl);
    pw[t] = acc;
  }
  __syncthreads();

  // ---- own H element: H[r][c] = sum over 8 strings with flip mask r^c -----
  float hr, hi, vr_, vi_;
  {
    int m = r ^ c;
    float hre = 0.0f, him = 0.0f;
    for (int u = 0; u < 8; ++u) {
      int k = 0;
      float pr = 1.0f, pim = 0.0f;
      #pragma unroll
      for (int q = 0; q < 3; ++q) {
        int bit = 2 - q;
        int f  = (m >> bit) & 1;
        int ch = (u >> bit) & 1;
        int rb = (r >> bit) & 1;
        int d  = f ? (ch ? 2 : 1) : (ch ? 3 : 0);  // I=0,X=1,Y=2,Z=3
        k = (k << 2) | d;
        if (d == 2) {
          float nr = rb ? -pim : pim;
          float ni = rb ?  pr  : -pr;
          pr = nr; pim = ni;
        } else if (d == 3 && rb) { pr = -pr; pim = -pim; }
      }
      float w = pw[k];
      hre += w * pr; him += w * pim;
    }
    hr = hre; hi = him;
    vr_ = (r == c) ? 1.0f : 0.0f;
    vi_ = 0.0f;
  }
  Sb[0][0][t] = hr; Sb[0][1][t] = hi;
  Sb[0][2][t] = vr_; Sb[0][3][t] = vi_;
  __syncthreads();

  // ---- Jacobi: 4 sweeps x 7 rounds, one barrier + one LDS wait per round --
  float* curB = &Sb[0][0][0];
  float* nxtB = &Sb[1][0][0];
  int round = 0;
  #pragma unroll 1
  for (int it = 0; it < 28; ++it) {
    int rho, gam; bool isPr, isPc;
    pairup(r, round, rho, isPr);
    pairup(c, round, gam, isPc);
    const int pR = isPr ? r : rho, qR = isPr ? rho : r;
    const int pC = isPc ? c : gam, qC = isPc ? gam : c;

    const float* HreC = curB;          // [64]
    const float* HimC = curB + 64;
    const float* VreC = curB + 128;
    const float* VimC = curB + 192;

    // one batched read group (all independent ds_reads)
    float aR  = HreC[pR*9],    bR  = HreC[qR*9];
    float zRr = HreC[pR*8+qR], zRi = HimC[pR*8+qR];
    float aC  = HreC[pC*9],    bC  = HreC[qC*9];
    float zCr = HreC[pC*8+qC], zCi = HimC[pC*8+qC];
    float hpc_r = HreC[rho*8+c],   hpc_i = HimC[rho*8+c];
    float hrg_r = HreC[r*8+gam],   hrg_i = HimC[r*8+gam];
    float hpg_r = HreC[rho*8+gam], hpg_i = HimC[rho*8+gam];
    float vrg_r = VreC[r*8+gam],   vrg_i = VimC[r*8+gam];

    float cR, sR, wRr, wRi; mkparam(aR, bR, zRr, zRi, cR, sR, wRr, wRi);
    float cC, sC, wCr, wCi; mkparam(aC, bC, zCr, zCi, cC, sC, wCr, wCi);

    // row stage (U_R^H A) applied to columns c and gam
    //  isPr: B = cR*own - sR*(wR*partner)   else: B = cR*own + sR*(conj(wR)*partner)
    float t1r = wRr*hpc_r - wRi*hpc_i, t1i = wRr*hpc_i + wRi*hpc_r;  // wR*h_pc
    float u1r = wRr*hpc_r + wRi*hpc_i, u1i = wRr*hpc_i - wRi*hpc_r;  // conj(wR)*h_pc
    float Bc_r = isPr ? (cR*hr - sR*t1r) : (cR*hr + sR*u1r);
    float Bc_i = isPr ? (cR*hi - sR*t1i) : (cR*hi + sR*u1i);
    float t2r = wRr*hpg_r - wRi*hpg_i, t2i = wRr*hpg_i + wRi*hpg_r;
    float u2r = wRr*hpg_r + wRi*hpg_i, u2i = wRr*hpg_i - wRi*hpg_r;
    float Bg_r = isPr ? (cR*hrg_r - sR*t2r) : (cR*hrg_r + sR*u2r);
    float Bg_i = isPr ? (cR*hrg_i - sR*t2i) : (cR*hrg_i + sR*u2i);

    // col stage (B U_C):
    //  isPc: A = cC*Bc - sC*(conj(wC)*Bg)   else: A = cC*Bc + sC*(wC*Bg)
    float t3r = wCr*Bg_r + wCi*Bg_i, t3i = wCr*Bg_i - wCi*Bg_r;      // conj(wC)*Bg
    float t4r = wCr*Bg_r - wCi*Bg_i, t4i = wCr*Bg_i + wCi*Bg_r;      // wC*Bg
    hr = isPc ? (cC*Bc_r - sC*t3r) : (cC*Bc_r + sC*t4r);
    hi = isPc ? (cC*Bc_i - sC*t3i) : (cC*Bc_i + sC*t4i);

    // V col stage
    float t5r = wCr*vrg_r + wCi*vrg_i, t5i = wCr*vrg_i - wCi*vrg_r;  // conj(wC)*vrg
    float t6r = wCr*vrg_r - wCi*vrg_i, t6i = wCr*vrg_i + wCi*vrg_r;  // wC*vrg
    float nvr = isPc ? (cC*vr_ - sC*t5r) : (cC*vr_ + sC*t6r);
    float nvi = isPc ? (cC*vi_ - sC*t5i) : (cC*vi_ + sC*t6i);
    vr_ = nvr; vi_ = nvi;

    nxtB[t]       = hr;
    nxtB[64 + t]  = hi;
    nxtB[128 + t] = vr_;
    nxtB[192 + t] = vi_;
    float* tmp = curB; curB = nxtB; nxtB = tmp;
    round = (round == 6) ? 0 : round + 1;
    __syncthreads();
  }

  const float* VreF = curB + 128;      // converged eigenvectors [r*8+c]
  const float* VimF = curB + 192;

  if (r == c) evs[r] = hr;             // eigenvalues from diagonal owners
  __syncthreads();

  // ---- F (Daleckii-Krein) + amp + 1/P -------------------------------------
  {
    int s = t >> 3, u = t & 7;
    float dm = 0.5f * (evs[s] - evs[u]);
    float av = 0.5f * (evs[s] + evs[u]);
    float sc = (fabsf(dm) < 1e-3f) ? (1.0f - dm*dm*(1.0f/6.0f)) : (__sinf(dm)/dm);
    FreS[t] =  __cosf(av) * sc;
    FimS[t] = -__sinf(av) * sc;
  }
  if (t < 8) {
    float are = 0.0f, aim = 0.0f;
    #pragma unroll
    for (int s = 0; s < 8; ++s) {
      float ce = __cosf(evs[s]), se = -__sinf(evs[s]);
      float c0r = VreF[s], c0i = -VimF[s];
      float wr2 = c0r*ce - c0i*se;
      float wi2 = c0r*se + c0i*ce;
      float vjr = VreF[t*8+s], vji = VimF[t*8+s];
      are += vjr*wr2 - vji*wi2;
      aim += vjr*wi2 + vji*wr2;
    }
    ampre[t] = are; ampim[t] = aim;
    float P = are*are + aim*aim;
    invPs[t] = 1.0f / fmaxf(P, 1e-30f);
  }
  __syncthreads();

  // ---- G[s][rho] = sum_u V[rho][u] F[s][u] conj(V[0][u]) ------------------
  {
    int s = t >> 3, rho = t & 7;
    float gr = 0.0f, gi = 0.0f;
    #pragma unroll
    for (int u = 0; u < 8; ++u) {
      float c0r = VreF[u], c0i = -VimF[u];
      float fr = FreS[s*8+u], fi = FimS[s*8+u];
      float fcr = fr*c0r - fi*c0i;
      float fci = fr*c0i + fi*c0r;
      float vr = VreF[rho*8+u], vi = VimF[rho*8+u];
      gr += vr*fcr - vi*fci;
      gi += vr*fci + vi*fcr;
    }
    GreS[t] = gr; GimS[t] = gi;
  }
  __syncthreads();

  // ---- Jacobian column k = t: gcol[p] in registers, g,h to LDS ------------
  float gcol[8];
  {
    const int k = t;
    const int d0 = (k >> 4) & 3, d1 = (k >> 2) & 3, d2 = k & 3;
    const int m = ((((d0 == 1) | (d0 == 2)) ? 1 : 0) << 2)
                | ((((d1 == 1) | (d1 == 2)) ? 1 : 0) << 1)
                |  (((d2 == 1) | (d2 == 2)) ? 1 : 0);
    float yre[8], yim[8];
    #pragma unroll
    for (int s = 0; s < 8; ++s) { yre[s] = 0.0f; yim[s] = 0.0f; }
    #pragma unroll
    for (int rr = 0; rr < 8; ++rr) {
      float pr = 1.0f, pim = 0.0f;       // ph_k(rr), in {±1, ±i}
      const int dd0[3] = {d0, d1, d2};
      #pragma unroll
      for (int q = 0; q < 3; ++q) {
        int rb = (rr >> (2 - q)) & 1;
        int d = dd0[q];
        if (d == 2) {
          float nr = rb ? -pim : pim;
          float ni = rb ?  pr  : -pr;
          pr = nr; pim = ni;
        } else if (d == 3 && rb) { pr = -pr; pim = -pim; }
      }
      int rm = rr ^ m;
      #pragma unroll
      for (int s = 0; s < 8; ++s) {      // y_s += conj(V[rr][s]) ph G[s][rr^m]
        float vr = VreF[rr*8+s], vi = -VimF[rr*8+s];
        float gr2 = GreS[s*8+rm], gi2 = GimS[s*8+rm];
        float ar = pr*gr2 - pim*gi2;
        float ai = pr*gi2 + pim*gr2;
        yre[s] += vr*ar - vi*ai;
        yim[s] += vr*ai + vi*ar;
      }
    }
    #pragma unroll
    for (int p = 0; p < 8; ++p) {        // damp_p = sum_s V[p][s] * (-i*y_s)
      float dr = 0.0f, di = 0.0f;
      #pragma unroll
      for (int s = 0; s < 8; ++s) {
        float ysr =  yim[s], ysi = -yre[s];   // * (-i)
        float vr = VreF[p*8+s], vi = VimF[p*8+s];
        dr += vr*ysr - vi*ysi;
        di += vr*ysi + vi*ysr;
      }
      float gg = 2.0f * (ampre[p]*dr + ampim[p]*di);
      gcol[p] = gg;
      gk[t][p] = gg;
      hk[t][p] = gg * invPs[p];
    }
  }
  __syncthreads();

  // ---- I_b row t: M[t][m] = sum_p gcol[p]*h[p][m], dwordx4 stores ---------
  {
    float* ob = out + (size_t)Bn * 65536 + (size_t)i * 4096 + (size_t)t * 64;
    #pragma unroll
    for (int m4 = 0; m4 < 16; ++m4) {
      float4 vv;
      #pragma unroll
      for (int l = 0; l < 4; ++l) {
        int m = m4*4 + l;
        const float4 ha = *(const float4*)&hk[m][0];   // broadcast reads
        const float4 hb = *(const float4*)&hk[m][4];
        (&vv.x)[l] = gcol[0]*ha.x + gcol[1]*ha.y + gcol[2]*ha.z + gcol[3]*ha.w
                   + gcol[4]*hb.x + gcol[5]*hb.y + gcol[6]*hb.z + gcol[7]*hb.w;
      }
      *(float4*)(ob + m4*4) = vv;
    }
  }
}

// ---------------------------------------------------------------------------
// Phase 2: 16 blocks per sample, 256 threads. Reads M from the I_b output
// region (written by phase 1, L2/L3-hot) and streams I_k = x_j*x_l*M[k,m].
// ---------------------------------------------------------------------------
__global__ __launch_bounds__(256) void fi_phase2(
    const void* __restrict__ xv,
    float* __restrict__ out, int Bn)
{
  const int bx = blockIdx.x;
  const int i  = bx >> 4;
  const int blk = bx & 15;              // j = blk>>2, kbase = (blk&3)*16
  const int t = threadIdx.x;

  __shared__ __align__(16) float Ms[16][68];

  const bool isdbl = detect_dbl(xv);

  const int rg = t >> 4;                // 0..15
  const int q4 = (t & 15) << 2;         // 0,4,..,60

  const float* Mg = out + (size_t)Bn * 65536 + (size_t)i * 4096;
  *(float4*)&Ms[rg][q4] =
      *(const float4*)(Mg + (size_t)(((blk & 3) << 4) + rg) * 64 + q4);

  const int j = blk >> 2;
  float xjf = (float)rdin(xv, i*4 + j, isdbl);
  float xx[4];
  #pragma unroll
  for (int l = 0; l < 4; ++l)
    xx[l] = xjf * (float)rdin(xv, i*4 + l, isdbl);

  __syncthreads();

  float* ok = out + (size_t)i * 65536 + (size_t)blk * 4096;
  #pragma unroll
  for (int it = 0; it < 4; ++it) {
    int local = it*16 + rg;             // row within this block's 64 rows
    int kk = local >> 2;                // 0..15
    int l  = local & 3;
    const float4 mv = *(const float4*)&Ms[kk][q4];
    float s = xx[l];
    *(float4*)(ok + (size_t)local * 64 + q4) =
        make_float4(s*mv.x, s*mv.y, s*mv.z, s*mv.w);
  }
}

extern "C" void kernel_launch(void* const* d_in, const int* in_sizes, int n_in,
                              void* d_out, int out_size, void* d_ws, size_t ws_size,
                              hipStream_t stream) {
  (void)n_in; (void)d_ws; (void)ws_size; (void)out_size;
  int Bn = in_sizes[0] / 4;   // 256
  fi_phase1<<<Bn, 64, 0, stream>>>(d_in[0], d_in[1], d_in[2], (float*)d_out, Bn);
  fi_phase2<<<Bn * 16, 256, 0, stream>>>(d_in[0], (float*)d_out, Bn);
}